// Round 2
// baseline (7946.414 us; speedup 1.0000x reference)
//
#include <hip/hip_runtime.h>

// ---------- constants ----------
#define TY 32
#define TX 1024
#define BB 64
#define IN 512
#define HH 512
#define CTX 1024

// ---------- bf16 helpers ----------
__device__ __forceinline__ float blo(unsigned u){ return __uint_as_float(u << 16); }
__device__ __forceinline__ float bhi(unsigned u){ return __uint_as_float(u & 0xffff0000u); }
__device__ __forceinline__ float b2f(unsigned short h){ return __uint_as_float(((unsigned)h) << 16); }
__device__ __forceinline__ unsigned short f2b(float f){
    unsigned u = __float_as_uint(f);
    u += 0x7fffu + ((u >> 16) & 1u);   // RNE
    return (unsigned short)(u >> 16);
}
__device__ __forceinline__ float fast_tanh(float x){
    float ax = fabsf(x);
    float e  = __expf(-2.0f * ax);
    float t  = __fdividef(1.0f - e, 1.0f + e);
    return copysignf(t, x);
}
__device__ __forceinline__ float fast_sigmoid(float x){
    return __fdividef(1.0f, 1.0f + __expf(-x));
}

// ---------- dtype-generic loads/stores (BF = input/output dtype is bf16) ----------
struct f8v { float4 a, b; };

template<bool BF> __device__ __forceinline__ float ldf(const void* p, size_t i){
    if (BF) return b2f(((const unsigned short*)p)[i]);
    return ((const float*)p)[i];
}
template<bool BF> __device__ __forceinline__ float4 ldf4(const void* p, size_t i){
    if (BF) {
        uint2 v = *(const uint2*)((const unsigned short*)p + i);
        return make_float4(blo(v.x), bhi(v.x), blo(v.y), bhi(v.y));
    }
    return *(const float4*)((const float*)p + i);
}
template<bool BF> __device__ __forceinline__ f8v ldf8(const void* p, size_t i){
    f8v r;
    if (BF) {
        uint4 v = *(const uint4*)((const unsigned short*)p + i);
        r.a = make_float4(blo(v.x), bhi(v.x), blo(v.y), bhi(v.y));
        r.b = make_float4(blo(v.z), bhi(v.z), blo(v.w), bhi(v.w));
    } else {
        r.a = *(const float4*)((const float*)p + i);
        r.b = *(const float4*)((const float*)p + i + 4);
    }
    return r;
}
// 8 input elements -> packed bf16 uint4 (for MFMA LDS staging)
template<bool BF> __device__ __forceinline__ uint4 ld8bf(const void* p, size_t i){
    if (BF) return *(const uint4*)((const unsigned short*)p + i);
    float4 x = *(const float4*)((const float*)p + i);
    float4 y = *(const float4*)((const float*)p + i + 4);
    uint4 r;
    r.x = (unsigned)f2b(x.x) | ((unsigned)f2b(x.y) << 16);
    r.y = (unsigned)f2b(x.z) | ((unsigned)f2b(x.w) << 16);
    r.z = (unsigned)f2b(y.x) | ((unsigned)f2b(y.y) << 16);
    r.w = (unsigned)f2b(y.z) | ((unsigned)f2b(y.w) << 16);
    return r;
}
template<bool BF> __device__ __forceinline__ void stf(void* p, size_t i, float v){
    if (BF) ((unsigned short*)p)[i] = f2b(v);
    else    ((float*)p)[i] = v;
}
// dot of fp32 LDS row with dtype-BF weight row
template<bool BF, int K>
__device__ __forceinline__ float dot8(const float* __restrict__ a, const void* __restrict__ w, size_t wbase){
    float s = 0.f;
#pragma unroll 4
    for (int k = 0; k < K; k += 8) {
        f8v v = ldf8<BF>(w, wbase + k);
        s += a[k    ] * v.a.x + a[k + 1] * v.a.y + a[k + 2] * v.a.z + a[k + 3] * v.a.w
           + a[k + 4] * v.b.x + a[k + 5] * v.b.y + a[k + 6] * v.b.z + a[k + 7] * v.b.w;
    }
    return s;
}

// ---------- dtype detection: x_mask is all ones ----------
__global__ void detect_k(const unsigned* __restrict__ xm, int* __restrict__ flag){
    if (threadIdx.x == 0 && blockIdx.x == 0)
        *flag = (xm[0] == 0x3F803F80u) ? 1 : 0;   // bf16 pair (1.0,1.0) vs fp32 1.0
}

// ---------- MFMA GEMM: out[M,N] = A[M,K] @ Wt[N,K]^T + bias[N]; out bf16 if OB else fp32 ----------
typedef short short8 __attribute__((ext_vector_type(8)));
typedef float f32x4  __attribute__((ext_vector_type(4)));

template<bool BF, bool OB>
__global__ __launch_bounds__(256) void gemm_k(
    const int* __restrict__ flag,
    const void* __restrict__ A, const void* __restrict__ Wt,
    const void* __restrict__ bias, void* __restrict__ out,
    int N, int K)
{
    if ((*flag != 0) != BF) return;
    __shared__ __align__(16) unsigned short As[128 * 32];
    __shared__ __align__(16) unsigned short Bs[128 * 32];
    const int tid  = threadIdx.x;
    const int bm   = blockIdx.x, bn = blockIdx.y;
    const int wave = tid >> 6, lane = tid & 63;
    const int wm   = wave >> 1, wn = wave & 1;
    const int q    = lane >> 4, r = lane & 15;
    const int lrow = tid >> 2, lk = (tid & 3) * 8;

    f32x4 acc[4][4];
#pragma unroll
    for (int i = 0; i < 4; i++)
#pragma unroll
        for (int j = 0; j < 4; j++) acc[i][j] = (f32x4){0.f, 0.f, 0.f, 0.f};

    const size_t abase = (size_t)(bm * 128 + lrow) * K + lk;
    const size_t bbase = (size_t)(bn * 128 + lrow) * K + lk;

    for (int kt = 0; kt < K; kt += 32) {
        uint4 va0 = ld8bf<BF>(A,  abase + kt);
        uint4 va1 = ld8bf<BF>(A,  abase + (size_t)64 * K + kt);
        uint4 vb0 = ld8bf<BF>(Wt, bbase + kt);
        uint4 vb1 = ld8bf<BF>(Wt, bbase + (size_t)64 * K + kt);
        __syncthreads();
        *(uint4*)&As[lrow * 32 + lk]        = va0;
        *(uint4*)&As[(lrow + 64) * 32 + lk] = va1;
        *(uint4*)&Bs[lrow * 32 + lk]        = vb0;
        *(uint4*)&Bs[(lrow + 64) * 32 + lk] = vb1;
        __syncthreads();
        short8 af[4], bf[4];
#pragma unroll
        for (int i = 0; i < 4; i++) af[i] = *(const short8*)&As[(wm * 64 + i * 16 + r) * 32 + q * 8];
#pragma unroll
        for (int j = 0; j < 4; j++) bf[j] = *(const short8*)&Bs[(wn * 64 + j * 16 + r) * 32 + q * 8];
#pragma unroll
        for (int i = 0; i < 4; i++)
#pragma unroll
            for (int j = 0; j < 4; j++)
                acc[i][j] = __builtin_amdgcn_mfma_f32_16x16x32_bf16(af[i], bf[j], acc[i][j], 0, 0, 0);
    }
#pragma unroll
    for (int j = 0; j < 4; j++) {
        const int col = bn * 128 + wn * 64 + j * 16 + r;
        const float bv = bias ? ldf<BF>(bias, col) : 0.0f;
#pragma unroll
        for (int i = 0; i < 4; i++) {
            const int row0 = bm * 128 + wm * 64 + i * 16 + q * 4;
#pragma unroll
            for (int g = 0; g < 4; g++) {
                const size_t oi = (size_t)(row0 + g) * N + col;
                if (OB) ((unsigned short*)out)[oi] = f2b(acc[i][j][g] + bv);
                else    ((float*)out)[oi] = acc[i][j][g] + bv;
            }
        }
    }
}

// ---------- init h0 ----------
template<bool BF>
__global__ __launch_bounds__(256) void init_k(const int* __restrict__ flag,
                                              const void* __restrict__ s, float* __restrict__ d){
    if ((*flag != 0) != BF) return;
    int i = blockIdx.x * 256 + threadIdx.x;
    d[i] = ldf<BF>(s, i);
}

// ---------- step 1: tmp1 = sigmoid(h@U^T + x_t); rhp = h*r1, u1 ----------
template<bool BF>
__global__ __launch_bounds__(256) void gate1_k(
    const int* __restrict__ flag,
    const float* __restrict__ h, const void* __restrict__ U,
    const float* __restrict__ xt,
    float* __restrict__ rhp, float* __restrict__ u1)
{
    if ((*flag != 0) != BF) return;
    __shared__ float lA[16 * 513];
    const int tid = threadIdx.x;
    const int bl = tid & 15, nl = tid >> 4;
    const int b = blockIdx.y * 16 + bl;
    const int n = blockIdx.x * 16 + nl;
    const float* src = h + blockIdx.y * 16 * 512;
    for (int idx = tid; idx < 16 * 512; idx += 256) lA[(idx >> 9) * 513 + (idx & 511)] = src[idx];
    __syncthreads();
    const float* a = lA + bl * 513;
    float s = dot8<BF, 512>(a, U, (size_t)n * 512);
    s += xt[(size_t)b * 1024 + n];
    float v = fast_sigmoid(s);
    if (n < 512) rhp[b * 512 + n] = a[n] * v;
    else         u1[b * 512 + (n - 512)] = v;
}

// ---------- step 2: h1 = blend(tanh(rhp@Ux^T + xx_t)) ----------
template<bool BF>
__global__ __launch_bounds__(256) void h1_k(
    const int* __restrict__ flag,
    const float* __restrict__ rhp, const void* __restrict__ Ux,
    const float* __restrict__ xxt, const float* __restrict__ u1,
    const float* __restrict__ h, const void* __restrict__ ymask, int t,
    float* __restrict__ h1)
{
    if ((*flag != 0) != BF) return;
    __shared__ float lA[16 * 513];
    const int tid = threadIdx.x;
    const int bl = tid & 15, nl = tid >> 4;
    const int b = blockIdx.y * 16 + bl;
    const int n = blockIdx.x * 16 + nl;
    const float* src = rhp + blockIdx.y * 16 * 512;
    for (int idx = tid; idx < 16 * 512; idx += 256) lA[(idx >> 9) * 513 + (idx & 511)] = src[idx];
    __syncthreads();
    float s = dot8<BF, 512>(lA + bl * 513, Ux, (size_t)n * 512);
    s += xxt[(size_t)b * 512 + n];
    float th  = fast_tanh(s);
    float u1v = u1[b * 512 + n];
    float hp  = h[b * 512 + n];
    float v   = u1v * hp + (1.f - u1v) * th;
    float ymv = ldf<BF>(ymask, (size_t)t * 64 + b);
    h1[b * 512 + n] = ymv * v + (1.f - ymv) * hp;
}

// ---------- step 3: hatt(fp32) = h1 @ W_comb_att^T ----------
template<bool BF>
__global__ __launch_bounds__(256) void hatt_k(
    const int* __restrict__ flag,
    const float* __restrict__ h1, const void* __restrict__ Wcomb,
    float* __restrict__ hatt)
{
    if ((*flag != 0) != BF) return;
    __shared__ float lA[16 * 513];
    const int tid = threadIdx.x;
    const int bl = tid & 15, nl = tid >> 4;
    const int b = blockIdx.y * 16 + bl;
    const int n = blockIdx.x * 16 + nl;
    const float* src = h1 + blockIdx.y * 16 * 512;
    for (int idx = tid; idx < 16 * 512; idx += 256) lA[(idx >> 9) * 513 + (idx & 511)] = src[idx];
    __syncthreads();
    hatt[b * 1024 + n] = dot8<BF, 512>(lA + bl * 513, Wcomb, (size_t)n * 512);
}

// ---------- step 4: scores[tx,b] = xm * sum_c Uatt[c]*tanh(pctx+hatt) ----------
template<bool BF>
__global__ __launch_bounds__(256) void scores_k(
    const int* __restrict__ flag,
    const unsigned short* __restrict__ pctx, const float* __restrict__ hatt,
    const void* __restrict__ Uatt, const void* __restrict__ xmask,
    float* __restrict__ scores)
{
    if ((*flag != 0) != BF) return;
    const int lane  = threadIdx.x & 63;
    const int rowid = blockIdx.x * 4 + (threadIdx.x >> 6);
    const int b     = rowid & 63;
    const unsigned short* prow = pctx + (size_t)rowid * 1024;
    const float* hrow = hatt + b * 1024;
    float s = 0.f;
#pragma unroll
    for (int half = 0; half < 2; half++) {
        const int c = half * 512 + lane * 8;
        uint4  pv = *(const uint4*)(prow + c);
        float4 h0 = *(const float4*)(hrow + c);
        float4 h1v = *(const float4*)(hrow + c + 4);
        f8v    uv = ldf8<BF>(Uatt, c);
        s += fast_tanh(blo(pv.x) + h0.x)  * uv.a.x;
        s += fast_tanh(bhi(pv.x) + h0.y)  * uv.a.y;
        s += fast_tanh(blo(pv.y) + h0.z)  * uv.a.z;
        s += fast_tanh(bhi(pv.y) + h0.w)  * uv.a.w;
        s += fast_tanh(blo(pv.z) + h1v.x) * uv.b.x;
        s += fast_tanh(bhi(pv.z) + h1v.y) * uv.b.y;
        s += fast_tanh(blo(pv.w) + h1v.z) * uv.b.z;
        s += fast_tanh(bhi(pv.w) + h1v.w) * uv.b.w;
    }
#pragma unroll
    for (int off = 32; off > 0; off >>= 1) s += __shfl_down(s, off);
    if (lane == 0) scores[rowid] = ldf<BF>(xmask, rowid) * s;
}

// ---------- step 5: softmax over tx (per b) + zero atted ----------
template<bool BF>
__global__ __launch_bounds__(256) void softmax_k(
    const int* __restrict__ flag,
    const float* __restrict__ scores, const void* __restrict__ xmask,
    float* __restrict__ watt, float* __restrict__ atted)
{
    if ((*flag != 0) != BF) return;
    const int b = blockIdx.x, tid = threadIdx.x;
    __shared__ float red[256];
    float sv[4];
    float m = -1e30f;
#pragma unroll
    for (int i = 0; i < 4; i++) { sv[i] = scores[(tid + i * 256) * 64 + b]; m = fmaxf(m, sv[i]); }
    red[tid] = m; __syncthreads();
    for (int s = 128; s > 0; s >>= 1) { if (tid < s) red[tid] = fmaxf(red[tid], red[tid + s]); __syncthreads(); }
    m = red[0]; __syncthreads();
    float e[4]; float sum = 0.f;
#pragma unroll
    for (int i = 0; i < 4; i++) {
        int tx = tid + i * 256;
        e[i] = __expf(sv[i] - m) * ldf<BF>(xmask, (size_t)tx * 64 + b);
        sum += e[i];
    }
    red[tid] = sum; __syncthreads();
    for (int s = 128; s > 0; s >>= 1) { if (tid < s) red[tid] += red[tid + s]; __syncthreads(); }
    float inv = __fdividef(1.0f, red[0]);
#pragma unroll
    for (int i = 0; i < 4; i++) watt[(tid + i * 256) * 64 + b] = e[i] * inv;
#pragma unroll
    for (int i = 0; i < 4; i++) atted[b * 1024 + tid + i * 256] = 0.f;
}

// ---------- step 6: atted[b,c] += sum_tx watt*context ----------
template<bool BF>
__global__ __launch_bounds__(256) void atted_k(
    const int* __restrict__ flag,
    const float* __restrict__ watt, const void* __restrict__ context,
    float* __restrict__ atted)
{
    if ((*flag != 0) != BF) return;
    const int b = blockIdx.x, chunk = blockIdx.y, tid = threadIdx.x;
    const int c = tid * 4;
    float a0 = 0.f, a1 = 0.f, a2 = 0.f, a3 = 0.f;
    for (int t = 0; t < 64; t++) {
        int tx = chunk * 64 + t;
        float wv = watt[tx * 64 + b];
        float4 cv = ldf4<BF>(context, (size_t)(tx * 64 + b) * 1024 + c);
        a0 += wv * cv.x; a1 += wv * cv.y;
        a2 += wv * cv.z; a3 += wv * cv.w;
    }
    atomicAdd(&atted[b * 1024 + c    ], a0);
    atomicAdd(&atted[b * 1024 + c + 1], a1);
    atomicAdd(&atted[b * 1024 + c + 2], a2);
    atomicAdd(&atted[b * 1024 + c + 3], a3);
}

// ---------- step 7: tmp2 = sigmoid(atted@Wc^T + h1@U_nl^T + b_nl); write atts ----------
template<bool BF>
__global__ __launch_bounds__(256) void gates2_k(
    const int* __restrict__ flag,
    const float* __restrict__ atted, const void* __restrict__ Wc,
    const float* __restrict__ h1, const void* __restrict__ Unl,
    const void* __restrict__ bnl,
    float* __restrict__ rh2p, float* __restrict__ u2,
    void* __restrict__ out, int t)
{
    if ((*flag != 0) != BF) return;
    __shared__ float lA1[8 * 1025];
    __shared__ float lA2[8 * 513];
    const int tid = threadIdx.x;
    const int bl = tid & 7, nl = tid >> 3;
    const int b = blockIdx.y * 8 + bl;
    const int n = blockIdx.x * 32 + nl;
    const float* s1 = atted + blockIdx.y * 8 * 1024;
    for (int idx = tid; idx < 8 * 1024; idx += 256) lA1[(idx >> 10) * 1025 + (idx & 1023)] = s1[idx];
    const float* s2 = h1 + blockIdx.y * 8 * 512;
    for (int idx = tid; idx < 8 * 512; idx += 256) lA2[(idx >> 9) * 513 + (idx & 511)] = s2[idx];
    __syncthreads();
    float s = ldf<BF>(bnl, n);
    s += dot8<BF, 1024>(lA1 + bl * 1025, Wc,  (size_t)n * 1024);
    s += dot8<BF, 512> (lA2 + bl * 513,  Unl, (size_t)n * 512);
    float v = fast_sigmoid(s);
    if (n < 512) rh2p[b * 512 + n] = lA2[bl * 513 + n] * v;
    else         u2[b * 512 + (n - 512)] = v;
    stf<BF>(out, (size_t)2097152 + (size_t)t * 65536 + (size_t)b * 1024 + n, lA1[bl * 1025 + n]);
}

// ---------- step 8: h2 = blend(tanh(atted@Wcx^T + rh2p@Ux_nl^T + bx_nl)) ----------
template<bool BF>
__global__ __launch_bounds__(256) void hfinal_k(
    const int* __restrict__ flag,
    const float* __restrict__ atted, const void* __restrict__ Wcx,
    const float* __restrict__ rh2p, const void* __restrict__ Uxnl,
    const void* __restrict__ bxnl,
    const float* __restrict__ h1, const float* __restrict__ u2,
    const void* __restrict__ ymask, int t,
    float* __restrict__ hnext, void* __restrict__ out)
{
    if ((*flag != 0) != BF) return;
    __shared__ float lA1[8 * 1025];
    __shared__ float lA2[8 * 513];
    const int tid = threadIdx.x;
    const int bl = tid & 7, nl = tid >> 3;
    const int b = blockIdx.y * 8 + bl;
    const int n = blockIdx.x * 32 + nl;
    const float* s1 = atted + blockIdx.y * 8 * 1024;
    for (int idx = tid; idx < 8 * 1024; idx += 256) lA1[(idx >> 10) * 1025 + (idx & 1023)] = s1[idx];
    const float* s2 = rh2p + blockIdx.y * 8 * 512;
    for (int idx = tid; idx < 8 * 512; idx += 256) lA2[(idx >> 9) * 513 + (idx & 511)] = s2[idx];
    __syncthreads();
    float s = ldf<BF>(bxnl, n);
    s += dot8<BF, 1024>(lA1 + bl * 1025, Wcx,  (size_t)n * 1024);
    s += dot8<BF, 512> (lA2 + bl * 513,  Uxnl, (size_t)n * 512);
    float hx  = fast_tanh(s);
    float h1v = h1[b * 512 + n];
    float u2v = u2[b * 512 + n];
    float h2  = u2v * h1v + (1.f - u2v) * hx;
    float ymv = ldf<BF>(ymask, (size_t)t * 64 + b);
    h2 = ymv * h2 + (1.f - ymv) * h1v;
    hnext[b * 512 + n] = h2;
    stf<BF>(out, (size_t)t * 32768 + (size_t)b * 512 + n, h2);
    stf<BF>(out, (size_t)1048576 + (size_t)t * 32768 + (size_t)b * 512 + n, h2);
}

// ---------- launcher ----------
extern "C" void kernel_launch(void* const* d_in, const int* in_sizes, int n_in,
                              void* d_out, int out_size, void* d_ws, size_t ws_size,
                              hipStream_t stream)
{
    (void)in_sizes; (void)n_in; (void)out_size; (void)ws_size;
    const void* y_emb   = d_in[0];
    const void* context = d_in[1];
    const void* init_st = d_in[2];
    const void* x_mask  = d_in[3];
    const void* y_mask  = d_in[4];
    const void* W       = d_in[5];
    const void* U       = d_in[6];
    const void* bvec    = d_in[7];
    const void* Wx      = d_in[8];
    const void* Ux      = d_in[9];
    const void* bx      = d_in[10];
    const void* Wc_att  = d_in[11];
    const void* b_att   = d_in[12];
    const void* W_comb  = d_in[13];
    const void* U_att   = d_in[14];
    const void* U_nl    = d_in[15];
    const void* b_nl    = d_in[16];
    const void* Ux_nl   = d_in[17];
    const void* bx_nl   = d_in[18];
    const void* Wc      = d_in[19];
    const void* Wcx     = d_in[20];

    char* w = (char*)d_ws;
    int* flag = (int*)w;                          w += 256;
    unsigned short* pctx = (unsigned short*)w;    w += (size_t)65536 * 1024 * 2;  // 134.2 MB
    float* xbuf   = (float*)w;                    w += (size_t)2048 * 1024 * 4;   // 8.4 MB
    float* xxbuf  = (float*)w;                    w += (size_t)2048 * 512 * 4;    // 4.2 MB
    float* hbuf0  = (float*)w;                    w += 64 * 512 * 4;
    float* hbuf1  = (float*)w;                    w += 64 * 512 * 4;
    float* rhp    = (float*)w;                    w += 64 * 512 * 4;
    float* u1     = (float*)w;                    w += 64 * 512 * 4;
    float* h1     = (float*)w;                    w += 64 * 512 * 4;
    float* rh2p   = (float*)w;                    w += 64 * 512 * 4;
    float* u2     = (float*)w;                    w += 64 * 512 * 4;
    float* hatt   = (float*)w;                    w += 64 * 1024 * 4;
    float* scores = (float*)w;                    w += 1024 * 64 * 4;
    float* watt   = (float*)w;                    w += 1024 * 64 * 4;
    float* atted  = (float*)w;                    w += 64 * 1024 * 4;

    detect_k<<<1, 64, 0, stream>>>((const unsigned*)x_mask, flag);

    // precompute: pctx (internal bf16), x, xx (internal fp32)
    gemm_k<true,  true ><<<dim3(512, 8), 256, 0, stream>>>(flag, context, Wc_att, b_att, pctx, 1024, 1024);
    gemm_k<false, true ><<<dim3(512, 8), 256, 0, stream>>>(flag, context, Wc_att, b_att, pctx, 1024, 1024);
    gemm_k<true,  false><<<dim3(16, 8),  256, 0, stream>>>(flag, y_emb, W,  bvec, xbuf,  1024, 512);
    gemm_k<false, false><<<dim3(16, 8),  256, 0, stream>>>(flag, y_emb, W,  bvec, xbuf,  1024, 512);
    gemm_k<true,  false><<<dim3(16, 4),  256, 0, stream>>>(flag, y_emb, Wx, bx,   xxbuf, 512,  512);
    gemm_k<false, false><<<dim3(16, 4),  256, 0, stream>>>(flag, y_emb, Wx, bx,   xxbuf, 512,  512);
    init_k<true ><<<128, 256, 0, stream>>>(flag, init_st, hbuf0);
    init_k<false><<<128, 256, 0, stream>>>(flag, init_st, hbuf0);

    for (int t = 0; t < TY; t++) {
        float* hp = (t & 1) ? hbuf1 : hbuf0;
        float* hn = (t & 1) ? hbuf0 : hbuf1;
        const float* xt  = xbuf  + (size_t)t * 64 * 1024;
        const float* xxt = xxbuf + (size_t)t * 64 * 512;

        gate1_k<true ><<<dim3(64, 4), 256, 0, stream>>>(flag, hp, U, xt, rhp, u1);
        gate1_k<false><<<dim3(64, 4), 256, 0, stream>>>(flag, hp, U, xt, rhp, u1);
        h1_k<true ><<<dim3(32, 4), 256, 0, stream>>>(flag, rhp, Ux, xxt, u1, hp, y_mask, t, h1);
        h1_k<false><<<dim3(32, 4), 256, 0, stream>>>(flag, rhp, Ux, xxt, u1, hp, y_mask, t, h1);
        hatt_k<true ><<<dim3(64, 4), 256, 0, stream>>>(flag, h1, W_comb, hatt);
        hatt_k<false><<<dim3(64, 4), 256, 0, stream>>>(flag, h1, W_comb, hatt);
        scores_k<true ><<<16384, 256, 0, stream>>>(flag, pctx, hatt, U_att, x_mask, scores);
        scores_k<false><<<16384, 256, 0, stream>>>(flag, pctx, hatt, U_att, x_mask, scores);
        softmax_k<true ><<<64, 256, 0, stream>>>(flag, scores, x_mask, watt, atted);
        softmax_k<false><<<64, 256, 0, stream>>>(flag, scores, x_mask, watt, atted);
        atted_k<true ><<<dim3(64, 16), 256, 0, stream>>>(flag, watt, context, atted);
        atted_k<false><<<dim3(64, 16), 256, 0, stream>>>(flag, watt, context, atted);
        gates2_k<true ><<<dim3(32, 8), 256, 0, stream>>>(flag, atted, Wc, h1, U_nl, b_nl, rh2p, u2, d_out, t);
        gates2_k<false><<<dim3(32, 8), 256, 0, stream>>>(flag, atted, Wc, h1, U_nl, b_nl, rh2p, u2, d_out, t);
        hfinal_k<true ><<<dim3(16, 8), 256, 0, stream>>>(flag, atted, Wcx, rh2p, Ux_nl, bx_nl, h1, u2, y_mask, t, hn, d_out);
        hfinal_k<false><<<dim3(16, 8), 256, 0, stream>>>(flag, atted, Wcx, rh2p, Ux_nl, bx_nl, h1, u2, y_mask, t, hn, d_out);
    }
}

// Round 3
// 6522.530 us; speedup vs baseline: 1.2183x; 1.2183x over previous
//
#include <hip/hip_runtime.h>

#define TY 32

// ---------- bf16 helpers ----------
__device__ __forceinline__ float blo(unsigned u){ return __uint_as_float(u << 16); }
__device__ __forceinline__ float bhi(unsigned u){ return __uint_as_float(u & 0xffff0000u); }
__device__ __forceinline__ float b2f(unsigned short h){ return __uint_as_float(((unsigned)h) << 16); }
__device__ __forceinline__ unsigned short f2b(float f){
    unsigned u = __float_as_uint(f);
    u += 0x7fffu + ((u >> 16) & 1u);   // RNE
    return (unsigned short)(u >> 16);
}
__device__ __forceinline__ float fast_tanh(float x){
    float ax = fabsf(x);
    float e  = __expf(-2.0f * ax);
    float t  = __fdividef(1.0f - e, 1.0f + e);
    return copysignf(t, x);
}
__device__ __forceinline__ float fast_sigmoid(float x){
    return __fdividef(1.0f, 1.0f + __expf(-x));
}
__device__ __forceinline__ void stf_rt(bool bf, void* p, size_t i, float v){
    if (bf) ((unsigned short*)p)[i] = f2b(v);
    else    ((float*)p)[i] = v;
}

// ---------- dtype detection: x_mask is all ones ----------
__global__ void detect_k(const unsigned* __restrict__ xm, int* __restrict__ flag){
    if (threadIdx.x == 0 && blockIdx.x == 0)
        *flag = (xm[0] == 0x3F803F80u) ? 1 : 0;   // bf16 pair (1,1) vs fp32 1.0
}

// ---------- cast native -> fp32 (both dtypes; exact) ----------
__global__ __launch_bounds__(256) void castf_k(const int* __restrict__ flag,
                                               const void* __restrict__ src,
                                               float* __restrict__ dst, int n){
    int i = blockIdx.x * 256 + threadIdx.x;
    if (i < n) dst[i] = (*flag) ? b2f(((const unsigned short*)src)[i]) : ((const float*)src)[i];
}

// ---------- cast fp32 -> bf16 (skips when input already bf16); n8 = n/8 ----------
__global__ __launch_bounds__(256) void castb_k(const int* __restrict__ flag,
                                               const void* __restrict__ src,
                                               unsigned short* __restrict__ dst, long long n8){
    if (*flag) return;
    const float* s = (const float*)src;
    long long i = (long long)blockIdx.x * 256 + threadIdx.x;
    long long stride = (long long)gridDim.x * 256;
    for (; i < n8; i += stride){
        const float* p = s + i * 8;
        float4 a = *(const float4*)p, b = *(const float4*)(p + 4);
        uint4 o;
        o.x = (unsigned)f2b(a.x) | ((unsigned)f2b(a.y) << 16);
        o.y = (unsigned)f2b(a.z) | ((unsigned)f2b(a.w) << 16);
        o.z = (unsigned)f2b(b.x) | ((unsigned)f2b(b.y) << 16);
        o.w = (unsigned)f2b(b.z) | ((unsigned)f2b(b.w) << 16);
        *(uint4*)(dst + i * 8) = o;
    }
}

// ---------- staging load: 8 elems -> packed bf16 uint4 ----------
__device__ __forceinline__ uint4 ld8s(bool bf, const void* __restrict__ nat,
                                      const unsigned short* __restrict__ alt, size_t i){
    if (bf)  return *(const uint4*)((const unsigned short*)nat + i);
    if (alt) return *(const uint4*)(alt + i);
    const float* f = (const float*)nat;
    float4 x = *(const float4*)(f + i), y = *(const float4*)(f + i + 4);
    uint4 r;
    r.x = (unsigned)f2b(x.x) | ((unsigned)f2b(x.y) << 16);
    r.y = (unsigned)f2b(x.z) | ((unsigned)f2b(x.w) << 16);
    r.z = (unsigned)f2b(y.x) | ((unsigned)f2b(y.y) << 16);
    r.w = (unsigned)f2b(y.z) | ((unsigned)f2b(y.w) << 16);
    return r;
}

// ---------- MFMA GEMM: out[M,N] = A[M,K] @ Wt[N,K]^T + bias[N] ----------
typedef short short8 __attribute__((ext_vector_type(8)));
typedef float f32x4  __attribute__((ext_vector_type(4)));

template<bool OB>
__global__ __launch_bounds__(256) void gemm_k(
    const int* __restrict__ flag,
    const void* __restrict__ Anat, const unsigned short* __restrict__ Abf,
    const void* __restrict__ Wnat, const unsigned short* __restrict__ Wbf,
    const float* __restrict__ bias, void* __restrict__ out,
    int N, int K)
{
    const bool bf = (*flag != 0);
    __shared__ __align__(16) unsigned short As[128 * 32];
    __shared__ __align__(16) unsigned short Bs[128 * 32];
    const int tid  = threadIdx.x;
    const int bm   = blockIdx.x, bn = blockIdx.y;
    const int wave = tid >> 6, lane = tid & 63;
    const int wm   = wave >> 1, wn = wave & 1;
    const int q    = lane >> 4, r = lane & 15;
    const int lrow = tid >> 2, lk = (tid & 3) * 8;

    f32x4 acc[4][4];
#pragma unroll
    for (int i = 0; i < 4; i++)
#pragma unroll
        for (int j = 0; j < 4; j++) acc[i][j] = (f32x4){0.f, 0.f, 0.f, 0.f};

    const size_t abase = (size_t)(bm * 128 + lrow) * K + lk;
    const size_t bbase = (size_t)(bn * 128 + lrow) * K + lk;

    for (int kt = 0; kt < K; kt += 32) {
        uint4 va0 = ld8s(bf, Anat, Abf, abase + kt);
        uint4 va1 = ld8s(bf, Anat, Abf, abase + (size_t)64 * K + kt);
        uint4 vb0 = ld8s(bf, Wnat, Wbf, bbase + kt);
        uint4 vb1 = ld8s(bf, Wnat, Wbf, bbase + (size_t)64 * K + kt);
        __syncthreads();
        *(uint4*)&As[lrow * 32 + lk]        = va0;
        *(uint4*)&As[(lrow + 64) * 32 + lk] = va1;
        *(uint4*)&Bs[lrow * 32 + lk]        = vb0;
        *(uint4*)&Bs[(lrow + 64) * 32 + lk] = vb1;
        __syncthreads();
        short8 af[4], bfr[4];
#pragma unroll
        for (int i = 0; i < 4; i++) af[i]  = *(const short8*)&As[(wm * 64 + i * 16 + r) * 32 + q * 8];
#pragma unroll
        for (int j = 0; j < 4; j++) bfr[j] = *(const short8*)&Bs[(wn * 64 + j * 16 + r) * 32 + q * 8];
#pragma unroll
        for (int i = 0; i < 4; i++)
#pragma unroll
            for (int j = 0; j < 4; j++)
                acc[i][j] = __builtin_amdgcn_mfma_f32_16x16x32_bf16(af[i], bfr[j], acc[i][j], 0, 0, 0);
    }
#pragma unroll
    for (int j = 0; j < 4; j++) {
        const int col = bn * 128 + wn * 64 + j * 16 + r;
        const float bv = bias ? bias[col] : 0.0f;
#pragma unroll
        for (int i = 0; i < 4; i++) {
            const int row0 = bm * 128 + wm * 64 + i * 16 + q * 4;
#pragma unroll
            for (int g = 0; g < 4; g++) {
                const size_t oi = (size_t)(row0 + g) * N + col;
                if (OB) ((unsigned short*)out)[oi] = f2b(acc[i][j][g] + bv);
                else    ((float*)out)[oi] = acc[i][j][g] + bv;
            }
        }
    }
}

// ---------- fp32 dot, 4 accumulators (a in LDS, w in global fp32) ----------
template<int K>
__device__ __forceinline__ float dotf(const float* __restrict__ a, const float* __restrict__ w){
    float s0 = 0.f, s1 = 0.f, s2 = 0.f, s3 = 0.f;
#pragma unroll 8
    for (int k = 0; k < K; k += 4){
        float4 wv = *(const float4*)(w + k);
        s0 += a[k    ] * wv.x;
        s1 += a[k + 1] * wv.y;
        s2 += a[k + 2] * wv.z;
        s3 += a[k + 3] * wv.w;
    }
    return (s0 + s1) + (s2 + s3);
}

// ---------- step 1: tmp1 = sigmoid(h@U^T + x_t); rhp = h*r1, u1 ----------
__global__ __launch_bounds__(256) void gate1_k(
    const float* __restrict__ h, const float* __restrict__ U,
    const float* __restrict__ xt,
    float* __restrict__ rhp, float* __restrict__ u1)
{
    __shared__ float lA[16 * 513];
    const int tid = threadIdx.x;
    const int bl = tid & 15, nl = tid >> 4;
    const int b = blockIdx.y * 16 + bl;
    const int n = blockIdx.x * 16 + nl;
    const float* src = h + blockIdx.y * 16 * 512;
    for (int idx = tid; idx < 16 * 512; idx += 256) lA[(idx >> 9) * 513 + (idx & 511)] = src[idx];
    __syncthreads();
    const float* a = lA + bl * 513;
    float s = dotf<512>(a, U + (size_t)n * 512);
    s += xt[(size_t)b * 1024 + n];
    float v = fast_sigmoid(s);
    if (n < 512) rhp[b * 512 + n] = a[n] * v;
    else         u1[b * 512 + (n - 512)] = v;
}

// ---------- step 2: h1 = blend(tanh(rhp@Ux^T + xx_t)) ----------
__global__ __launch_bounds__(256) void h1_k(
    const float* __restrict__ rhp, const float* __restrict__ Ux,
    const float* __restrict__ xxt, const float* __restrict__ u1,
    const float* __restrict__ h, const float* __restrict__ ymf, int t,
    float* __restrict__ h1)
{
    __shared__ float lA[16 * 513];
    const int tid = threadIdx.x;
    const int bl = tid & 15, nl = tid >> 4;
    const int b = blockIdx.y * 16 + bl;
    const int n = blockIdx.x * 16 + nl;
    const float* src = rhp + blockIdx.y * 16 * 512;
    for (int idx = tid; idx < 16 * 512; idx += 256) lA[(idx >> 9) * 513 + (idx & 511)] = src[idx];
    __syncthreads();
    float s = dotf<512>(lA + bl * 513, Ux + (size_t)n * 512);
    s += xxt[(size_t)b * 512 + n];
    float th  = fast_tanh(s);
    float u1v = u1[b * 512 + n];
    float hp  = h[b * 512 + n];
    float v   = u1v * hp + (1.f - u1v) * th;
    float ymv = ymf[t * 64 + b];
    h1[b * 512 + n] = ymv * v + (1.f - ymv) * hp;
}

// ---------- step 3: hatt(fp32) = h1 @ W_comb_att^T ----------
__global__ __launch_bounds__(256) void hatt_k(
    const float* __restrict__ h1, const float* __restrict__ Wcomb,
    float* __restrict__ hatt)
{
    __shared__ float lA[16 * 513];
    const int tid = threadIdx.x;
    const int bl = tid & 15, nl = tid >> 4;
    const int b = blockIdx.y * 16 + bl;
    const int n = blockIdx.x * 16 + nl;
    const float* src = h1 + blockIdx.y * 16 * 512;
    for (int idx = tid; idx < 16 * 512; idx += 256) lA[(idx >> 9) * 513 + (idx & 511)] = src[idx];
    __syncthreads();
    hatt[b * 1024 + n] = dotf<512>(lA + bl * 513, Wcomb + (size_t)n * 512);
}

// ---------- step 4: scores[tx,b] = xm * sum_c Uatt[c]*tanh(pctx+hatt) ----------
__global__ __launch_bounds__(256) void scores_k(
    const unsigned short* __restrict__ pctx, const float* __restrict__ hatt,
    const float* __restrict__ Uattf, const float* __restrict__ xmf,
    float* __restrict__ scores)
{
    const int lane  = threadIdx.x & 63;
    const int rowid = blockIdx.x * 4 + (threadIdx.x >> 6);
    const int b     = rowid & 63;
    const unsigned short* prow = pctx + (size_t)rowid * 1024;
    const float* hrow = hatt + b * 1024;
    float s = 0.f;
#pragma unroll
    for (int half = 0; half < 2; half++) {
        const int c = half * 512 + lane * 8;
        uint4  pv = *(const uint4*)(prow + c);
        float4 h0 = *(const float4*)(hrow + c);
        float4 h1v = *(const float4*)(hrow + c + 4);
        float4 u0 = *(const float4*)(Uattf + c);
        float4 u1v = *(const float4*)(Uattf + c + 4);
        s += fast_tanh(blo(pv.x) + h0.x)  * u0.x;
        s += fast_tanh(bhi(pv.x) + h0.y)  * u0.y;
        s += fast_tanh(blo(pv.y) + h0.z)  * u0.z;
        s += fast_tanh(bhi(pv.y) + h0.w)  * u0.w;
        s += fast_tanh(blo(pv.z) + h1v.x) * u1v.x;
        s += fast_tanh(bhi(pv.z) + h1v.y) * u1v.y;
        s += fast_tanh(blo(pv.w) + h1v.z) * u1v.z;
        s += fast_tanh(bhi(pv.w) + h1v.w) * u1v.w;
    }
#pragma unroll
    for (int off = 32; off > 0; off >>= 1) s += __shfl_down(s, off);
    if (lane == 0) scores[rowid] = xmf[rowid] * s;
}

// ---------- step 5: softmax over tx (per b) + zero atted ----------
__global__ __launch_bounds__(256) void softmax_k(
    const float* __restrict__ scores, const float* __restrict__ xmf,
    float* __restrict__ watt, float* __restrict__ atted)
{
    const int b = blockIdx.x, tid = threadIdx.x;
    __shared__ float red[256];
    float sv[4];
    float m = -1e30f;
#pragma unroll
    for (int i = 0; i < 4; i++) { sv[i] = scores[(tid + i * 256) * 64 + b]; m = fmaxf(m, sv[i]); }
    red[tid] = m; __syncthreads();
    for (int s = 128; s > 0; s >>= 1) { if (tid < s) red[tid] = fmaxf(red[tid], red[tid + s]); __syncthreads(); }
    m = red[0]; __syncthreads();
    float e[4]; float sum = 0.f;
#pragma unroll
    for (int i = 0; i < 4; i++) {
        int tx = tid + i * 256;
        e[i] = __expf(sv[i] - m) * xmf[tx * 64 + b];
        sum += e[i];
    }
    red[tid] = sum; __syncthreads();
    for (int s = 128; s > 0; s >>= 1) { if (tid < s) red[tid] += red[tid + s]; __syncthreads(); }
    float inv = __fdividef(1.0f, red[0]);
#pragma unroll
    for (int i = 0; i < 4; i++) watt[(tid + i * 256) * 64 + b] = e[i] * inv;
#pragma unroll
    for (int i = 0; i < 4; i++) atted[b * 1024 + tid + i * 256] = 0.f;
}

// ---------- step 6: atted[b,c] += sum_tx watt*context ----------
__global__ __launch_bounds__(256) void atted_k(
    const int* __restrict__ flag,
    const float* __restrict__ watt,
    const void* __restrict__ ctxnat, const unsigned short* __restrict__ ctxbf,
    float* __restrict__ atted)
{
    const bool bf = (*flag != 0);
    const unsigned short* cb = bf ? (const unsigned short*)ctxnat : ctxbf;
    const int b = blockIdx.x, chunk = blockIdx.y, tid = threadIdx.x;
    const int c = tid * 4;
    float a0 = 0.f, a1 = 0.f, a2 = 0.f, a3 = 0.f;
    if (cb) {
        for (int t = 0; t < 64; t++) {
            int tx = chunk * 64 + t;
            float wv = watt[tx * 64 + b];
            uint2 cv = *(const uint2*)(cb + (size_t)(tx * 64 + b) * 1024 + c);
            a0 += wv * blo(cv.x); a1 += wv * bhi(cv.x);
            a2 += wv * blo(cv.y); a3 += wv * bhi(cv.y);
        }
    } else {
        const float* cf = (const float*)ctxnat;
        for (int t = 0; t < 64; t++) {
            int tx = chunk * 64 + t;
            float wv = watt[tx * 64 + b];
            float4 cv = *(const float4*)(cf + (size_t)(tx * 64 + b) * 1024 + c);
            a0 += wv * cv.x; a1 += wv * cv.y;
            a2 += wv * cv.z; a3 += wv * cv.w;
        }
    }
    atomicAdd(&atted[b * 1024 + c    ], a0);
    atomicAdd(&atted[b * 1024 + c + 1], a1);
    atomicAdd(&atted[b * 1024 + c + 2], a2);
    atomicAdd(&atted[b * 1024 + c + 3], a3);
}

// ---------- step 7: tmp2 = sigmoid(atted@Wc^T + h1@U_nl^T + b_nl); write atts ----------
__global__ __launch_bounds__(256) void gates2_k(
    const int* __restrict__ flag,
    const float* __restrict__ atted, const float* __restrict__ Wcf,
    const float* __restrict__ h1, const float* __restrict__ Unlf,
    const float* __restrict__ bnlf,
    float* __restrict__ rh2p, float* __restrict__ u2,
    void* __restrict__ out, int t)
{
    const bool bf = (*flag != 0);
    __shared__ float lA1[8 * 1025];
    __shared__ float lA2[8 * 513];
    const int tid = threadIdx.x;
    const int bl = tid & 7, nl = tid >> 3;
    const int b = blockIdx.y * 8 + bl;
    const int n = blockIdx.x * 32 + nl;
    const float* s1 = atted + blockIdx.y * 8 * 1024;
    for (int idx = tid; idx < 8 * 1024; idx += 256) lA1[(idx >> 10) * 1025 + (idx & 1023)] = s1[idx];
    const float* s2 = h1 + blockIdx.y * 8 * 512;
    for (int idx = tid; idx < 8 * 512; idx += 256) lA2[(idx >> 9) * 513 + (idx & 511)] = s2[idx];
    __syncthreads();
    float s = bnlf[n];
    s += dotf<1024>(lA1 + bl * 1025, Wcf  + (size_t)n * 1024);
    s += dotf<512> (lA2 + bl * 513,  Unlf + (size_t)n * 512);
    float v = fast_sigmoid(s);
    if (n < 512) rh2p[b * 512 + n] = lA2[bl * 513 + n] * v;
    else         u2[b * 512 + (n - 512)] = v;
    stf_rt(bf, out, (size_t)2097152 + (size_t)t * 65536 + (size_t)b * 1024 + n, lA1[bl * 1025 + n]);
}

// ---------- step 8: h2 = blend(tanh(atted@Wcx^T + rh2p@Ux_nl^T + bx_nl)) ----------
__global__ __launch_bounds__(256) void hfinal_k(
    const int* __restrict__ flag,
    const float* __restrict__ atted, const float* __restrict__ Wcxf,
    const float* __restrict__ rh2p, const float* __restrict__ Uxnlf,
    const float* __restrict__ bxnlf,
    const float* __restrict__ h1, const float* __restrict__ u2,
    const float* __restrict__ ymf, int t,
    float* __restrict__ hnext, void* __restrict__ out)
{
    const bool bf = (*flag != 0);
    __shared__ float lA1[8 * 1025];
    __shared__ float lA2[8 * 513];
    const int tid = threadIdx.x;
    const int bl = tid & 7, nl = tid >> 3;
    const int b = blockIdx.y * 8 + bl;
    const int n = blockIdx.x * 32 + nl;
    const float* s1 = atted + blockIdx.y * 8 * 1024;
    for (int idx = tid; idx < 8 * 1024; idx += 256) lA1[(idx >> 10) * 1025 + (idx & 1023)] = s1[idx];
    const float* s2 = rh2p + blockIdx.y * 8 * 512;
    for (int idx = tid; idx < 8 * 512; idx += 256) lA2[(idx >> 9) * 513 + (idx & 511)] = s2[idx];
    __syncthreads();
    float s = bxnlf[n];
    s += dotf<1024>(lA1 + bl * 1025, Wcxf  + (size_t)n * 1024);
    s += dotf<512> (lA2 + bl * 513,  Uxnlf + (size_t)n * 512);
    float hx  = fast_tanh(s);
    float h1v = h1[b * 512 + n];
    float u2v = u2[b * 512 + n];
    float h2  = u2v * h1v + (1.f - u2v) * hx;
    float ymv = ymf[t * 64 + b];
    h2 = ymv * h2 + (1.f - ymv) * h1v;
    hnext[b * 512 + n] = h2;
    stf_rt(bf, out, (size_t)t * 32768 + (size_t)b * 512 + n, h2);
    stf_rt(bf, out, (size_t)1048576 + (size_t)t * 32768 + (size_t)b * 512 + n, h2);
}

// ---------- launcher ----------
extern "C" void kernel_launch(void* const* d_in, const int* in_sizes, int n_in,
                              void* d_out, int out_size, void* d_ws, size_t ws_size,
                              hipStream_t stream)
{
    (void)in_sizes; (void)n_in; (void)out_size;
    const void* y_emb   = d_in[0];
    const void* context = d_in[1];
    const void* init_st = d_in[2];
    const void* x_mask  = d_in[3];
    const void* y_mask  = d_in[4];
    const void* W       = d_in[5];
    const void* U       = d_in[6];
    const void* bvec    = d_in[7];
    const void* Wx      = d_in[8];
    const void* Ux      = d_in[9];
    const void* bx      = d_in[10];
    const void* Wc_att  = d_in[11];
    const void* b_att   = d_in[12];
    const void* W_comb  = d_in[13];
    const void* U_att   = d_in[14];
    const void* U_nl    = d_in[15];
    const void* b_nl    = d_in[16];
    const void* Ux_nl   = d_in[17];
    const void* bx_nl   = d_in[18];
    const void* Wc      = d_in[19];
    const void* Wcx     = d_in[20];

    char* w = (char*)d_ws;
    int* flag = (int*)w;                            w += 256;
    unsigned short* pctx  = (unsigned short*)w;     w += (size_t)65536 * 1024 * 2;
    unsigned short* ybf   = (unsigned short*)w;     w += (size_t)2048 * 512 * 2;
    unsigned short* Wbf   = (unsigned short*)w;     w += (size_t)1024 * 512 * 2;
    unsigned short* Wxbf  = (unsigned short*)w;     w += (size_t)512 * 512 * 2;
    unsigned short* Wcabf = (unsigned short*)w;     w += (size_t)1024 * 1024 * 2;
    float* xbuf   = (float*)w;                      w += (size_t)2048 * 1024 * 4;
    float* xxbuf  = (float*)w;                      w += (size_t)2048 * 512 * 4;
    float* Uf     = (float*)w;                      w += (size_t)1024 * 512 * 4;
    float* Uxf    = (float*)w;                      w += (size_t)512 * 512 * 4;
    float* Wcombf = (float*)w;                      w += (size_t)1024 * 512 * 4;
    float* Unlf   = (float*)w;                      w += (size_t)1024 * 512 * 4;
    float* Uxnlf  = (float*)w;                      w += (size_t)512 * 512 * 4;
    float* Wcf    = (float*)w;                      w += (size_t)1024 * 1024 * 4;
    float* Wcxf   = (float*)w;                      w += (size_t)512 * 1024 * 4;
    float* Uattf  = (float*)w;                      w += 1024 * 4;
    float* xmf    = (float*)w;                      w += 65536 * 4;
    float* ymf    = (float*)w;                      w += 2048 * 4;
    float* battf  = (float*)w;                      w += 1024 * 4;
    float* bvecf  = (float*)w;                      w += 1024 * 4;
    float* bxf    = (float*)w;                      w += 512 * 4;
    float* bnlf   = (float*)w;                      w += 1024 * 4;
    float* bxnlf  = (float*)w;                      w += 512 * 4;
    float* hbuf0  = (float*)w;                      w += 64 * 512 * 4;
    float* hbuf1  = (float*)w;                      w += 64 * 512 * 4;
    float* rhp    = (float*)w;                      w += 64 * 512 * 4;
    float* u1     = (float*)w;                      w += 64 * 512 * 4;
    float* h1     = (float*)w;                      w += 64 * 512 * 4;
    float* rh2p   = (float*)w;                      w += 64 * 512 * 4;
    float* u2     = (float*)w;                      w += 64 * 512 * 4;
    float* hatt   = (float*)w;                      w += 64 * 1024 * 4;
    float* scores = (float*)w;                      w += 1024 * 64 * 4;
    float* watt   = (float*)w;                      w += 1024 * 64 * 4;
    float* atted  = (float*)w;                      w += 64 * 1024 * 4;
    // optional bf16 copy of context (fp32 path): needs +134.2 MB
    size_t base_bytes = (size_t)(w - (char*)d_ws);
    size_t ctx_bytes  = (size_t)65536 * 1024 * 2;
    unsigned short* ctxbf = nullptr;
    if (ws_size >= base_bytes + ctx_bytes + 4096) ctxbf = (unsigned short*)w;

    detect_k<<<1, 64, 0, stream>>>((const unsigned*)x_mask, flag);

    // one-time fp32 normalizations (exact in both dtype paths)
    castf_k<<<2048, 256, 0, stream>>>(flag, U,      Uf,     524288);
    castf_k<<<1024, 256, 0, stream>>>(flag, Ux,     Uxf,    262144);
    castf_k<<<2048, 256, 0, stream>>>(flag, W_comb, Wcombf, 524288);
    castf_k<<<2048, 256, 0, stream>>>(flag, U_nl,   Unlf,   524288);
    castf_k<<<1024, 256, 0, stream>>>(flag, Ux_nl,  Uxnlf,  262144);
    castf_k<<<4096, 256, 0, stream>>>(flag, Wc,     Wcf,    1048576);
    castf_k<<<2048, 256, 0, stream>>>(flag, Wcx,    Wcxf,   524288);
    castf_k<<<4,    256, 0, stream>>>(flag, U_att,  Uattf,  1024);
    castf_k<<<256,  256, 0, stream>>>(flag, x_mask, xmf,    65536);
    castf_k<<<8,    256, 0, stream>>>(flag, y_mask, ymf,    2048);
    castf_k<<<4,    256, 0, stream>>>(flag, b_att,  battf,  1024);
    castf_k<<<4,    256, 0, stream>>>(flag, bvec,   bvecf,  1024);
    castf_k<<<2,    256, 0, stream>>>(flag, bx,     bxf,    512);
    castf_k<<<4,    256, 0, stream>>>(flag, b_nl,   bnlf,   1024);
    castf_k<<<2,    256, 0, stream>>>(flag, bx_nl,  bxnlf,  512);
    castf_k<<<128,  256, 0, stream>>>(flag, init_st, hbuf0, 32768);

    // one-time bf16 copies for MFMA staging (no-op when inputs already bf16)
    castb_k<<<512,  256, 0, stream>>>(flag, y_emb,  ybf,   131072);
    castb_k<<<256,  256, 0, stream>>>(flag, W,      Wbf,   65536);
    castb_k<<<128,  256, 0, stream>>>(flag, Wx,     Wxbf,  32768);
    castb_k<<<512,  256, 0, stream>>>(flag, Wc_att, Wcabf, 131072);
    if (ctxbf)
        castb_k<<<8192, 256, 0, stream>>>(flag, context, ctxbf, 8388608);

    // precompute: pctx (bf16), x, xx (fp32)
    gemm_k<true ><<<dim3(512, 8), 256, 0, stream>>>(flag, context, ctxbf, Wc_att, Wcabf, battf, pctx, 1024, 1024);
    gemm_k<false><<<dim3(16, 8),  256, 0, stream>>>(flag, y_emb, ybf, W,  Wbf,  bvecf, xbuf,  1024, 512);
    gemm_k<false><<<dim3(16, 4),  256, 0, stream>>>(flag, y_emb, ybf, Wx, Wxbf, bxf,   xxbuf, 512,  512);

    for (int t = 0; t < TY; t++) {
        float* hp = (t & 1) ? hbuf1 : hbuf0;
        float* hn = (t & 1) ? hbuf0 : hbuf1;
        const float* xt  = xbuf  + (size_t)t * 64 * 1024;
        const float* xxt = xxbuf + (size_t)t * 64 * 512;

        gate1_k <<<dim3(64, 4),  256, 0, stream>>>(hp, Uf, xt, rhp, u1);
        h1_k    <<<dim3(32, 4),  256, 0, stream>>>(rhp, Uxf, xxt, u1, hp, ymf, t, h1);
        hatt_k  <<<dim3(64, 4),  256, 0, stream>>>(h1, Wcombf, hatt);
        scores_k<<<16384,        256, 0, stream>>>(pctx, hatt, Uattf, xmf, scores);
        softmax_k<<<64,          256, 0, stream>>>(scores, xmf, watt, atted);
        atted_k <<<dim3(64, 16), 256, 0, stream>>>(flag, watt, context, ctxbf, atted);
        gates2_k<<<dim3(32, 8),  256, 0, stream>>>(flag, atted, Wcf, h1, Unlf, bnlf, rh2p, u2, d_out, t);
        hfinal_k<<<dim3(16, 8),  256, 0, stream>>>(flag, atted, Wcxf, rh2p, Uxnlf, bxnlf, h1, u2, ymf, t, hn, d_out);
    }
}